// Round 8
// baseline (387.008 us; speedup 1.0000x reference)
//
#include <hip/hip_runtime.h>

#define D_MODEL 512
#define NHEAD 8
#define DK 64
#define SEQ 2048

// log2-domain softmax constants: p = exp2(s*scale*log2e - m2)
#define SCL2 0.18033688011112042f        // 0.125 * log2(e)
#define MASKL2 -1.4426950408889634e9f    // -1e9 * log2(e)

typedef __attribute__((ext_vector_type(8))) short bf16x8;
typedef __attribute__((ext_vector_type(4))) float f32x4;

// ---- bf16 split helpers ----------------------------------------------------
__device__ __forceinline__ unsigned short f2bf_rne(float x) {
  union { float f; unsigned u; } v; v.f = x;
  return (unsigned short)((v.u + 0x7FFFu + ((v.u >> 16) & 1u)) >> 16);
}
__device__ __forceinline__ float bf2f(unsigned short b) {
  union { unsigned u; float f; } v; v.u = ((unsigned)b) << 16;
  return v.f;
}
__device__ __forceinline__ void split_rne(float x, unsigned short& hi,
                                          unsigned short& lo) {
  hi = f2bf_rne(x);
  lo = f2bf_rne(x - bf2f(hi));
}
// Cheap truncating split (error ~2^-14 rel after 3-term MFMA). Hot path only.
__device__ __forceinline__ void split_trunc(float x, unsigned short& hi,
                                            unsigned short& lo) {
  union { float f; unsigned u; } v; v.f = x;
  hi = (unsigned short)(v.u >> 16);
  union { float f; unsigned u; } r; r.f = x - bf2f(hi);
  lo = (unsigned short)(r.u >> 16);
}

// Async global->LDS, 16B/lane; LDS dest = wave-uniform base + lane*16.
__device__ __forceinline__ void gload_lds16(const void* g, void* l) {
  __builtin_amdgcn_global_load_lds(
      (const __attribute__((address_space(1))) unsigned int*)g,
      (__attribute__((address_space(3))) unsigned int*)l, 16, 0, 0);
}

// ---------------------------------------------------------------------------
// Pass 0: split fp32 (8192x512) into bf16 hi/lo in GEMM-ready tiled+swizzled
// layout: tile (m/64, c/64) contiguous 4096 ushorts; off = r*64 + (c^8*(r&7)).
// ---------------------------------------------------------------------------
__global__ __launch_bounds__(256) void split_tile(const float* __restrict__ A,
                                                  unsigned short* __restrict__ Xh,
                                                  unsigned short* __restrict__ Xl) {
  const int e = blockIdx.x * 256 + threadIdx.x;
  const int m = e >> 7;
  const int c0 = (e & 127) << 2;
  const float4 a = *(const float4*)(A + (size_t)m * 512 + c0);
  ushort4 h4, l4;
  split_rne(a.x, h4.x, l4.x);
  split_rne(a.y, h4.y, l4.y);
  split_rne(a.z, h4.z, l4.z);
  split_rne(a.w, h4.w, l4.w);
  const int r = m & 63, mt = m >> 6, kt = c0 >> 6, cc = c0 & 63;
  const int off = (mt * 8 + kt) * 4096 + r * 64 + (cc ^ ((r & 7) << 3));
  *(ushort4*)&Xh[off] = h4;
  *(ushort4*)&Xl[off] = l4;
}

// ---------------------------------------------------------------------------
// Split-bf16 MFMA GEMM: C = A @ W^T. BM=128, BN=64, BK=64, 256 thr (4 waves).
// A pre-split tiled hi/lo, double-buffered via global_load_lds issued AFTER
// the second barrier (stays in flight across the MFMA phase). W fp32,
// register-prefetched one k-step ahead, trunc-split into LDS.
// Per k-step/wave: 48 MFMA vs 24 ds_read_b128. LDS 80KB -> 2 blocks/CU.
// ---------------------------------------------------------------------------
#define EPI_Q 0
#define EPI_K 1
#define EPI_VT 2
#define EPI_OUT 3

template <int EPI>
__global__ __launch_bounds__(256) void gemm_split(
    const unsigned short* __restrict__ Ah, const unsigned short* __restrict__ Al,
    const float* __restrict__ W,
    unsigned short* __restrict__ Ch, unsigned short* __restrict__ Cl,
    float* __restrict__ Cf) {
  __shared__ unsigned short Ash[2][8192], Asl[2][8192];
  __shared__ unsigned short Wsh[4096], Wsl[4096];
  const int tid = threadIdx.x;
  const int w = tid >> 6, lane = tid & 63, lg = lane >> 4, lc = lane & 15;
  const int mt = blockIdx.x, nt = blockIdx.y;

  f32x4 acc[2][4] = {};

  const int wr = tid >> 2;         // W stage: row 0..63
  const int wc0 = (tid & 3) << 4;  // W stage: col base
  const float* Wrow = W + (size_t)(nt * 64 + wr) * 512;

  float4 wreg[4];
#pragma unroll
  for (int j = 0; j < 4; ++j)
    wreg[j] = *(const float4*)(Wrow + wc0 + j * 4);

  // issue A(kt) into buf: 8 gloads/wave (2 subtiles x hi/lo x 2 chunks).
  auto issueA = [&](int kt, int buf) {
#pragma unroll
    for (int sub = 0; sub < 2; ++sub) {
      const size_t tb = ((size_t)((2 * mt + sub) * 8 + kt)) * 4096;
      const unsigned short* sh = Ah + tb + w * 512 + lane * 8;
      const unsigned short* sl = Al + tb + w * 512 + lane * 8;
      gload_lds16(sh, &Ash[buf][sub * 4096 + w * 512]);
      gload_lds16(sh + 2048, &Ash[buf][sub * 4096 + w * 512 + 2048]);
      gload_lds16(sl, &Asl[buf][sub * 4096 + w * 512]);
      gload_lds16(sl + 2048, &Asl[buf][sub * 4096 + w * 512 + 2048]);
    }
  };
  issueA(0, 0);

  for (int kt = 0; kt < 8; ++kt) {
    const int cur = kt & 1;
    __syncthreads();  // A(kt) drained; Wsh free (prev MFMA done)
    // stage W(kt) from prefetched regs (trunc split, swizzled)
#pragma unroll
    for (int j = 0; j < 4; ++j) {
      ushort4 h4, l4;
      split_trunc(wreg[j].x, h4.x, l4.x);
      split_trunc(wreg[j].y, h4.y, l4.y);
      split_trunc(wreg[j].z, h4.z, l4.z);
      split_trunc(wreg[j].w, h4.w, l4.w);
      const int off = wr * 64 + ((wc0 + j * 4) ^ ((wr & 7) << 3));
      *(ushort4*)&Wsh[off] = h4;
      *(ushort4*)&Wsl[off] = l4;
    }
    __syncthreads();  // Wsh(kt) visible
    if (kt < 7) {
      issueA(kt + 1, cur ^ 1);  // in flight across MFMA below
#pragma unroll
      for (int j = 0; j < 4; ++j)
        wreg[j] = *(const float4*)(Wrow + (kt + 1) * 64 + wc0 + j * 4);
    }
    __builtin_amdgcn_s_setprio(1);
#pragma unroll
    for (int ar = 0; ar < 2; ++ar) {
      const int arow = w * 16 + lc;
      const int abase = ar * 4096 + arow * 64;
#pragma unroll
      for (int s = 0; s < 2; ++s) {
        const int aoff = abase + ((s * 32 + lg * 8) ^ ((arow & 7) << 3));
        const bf16x8 a_hi = *(const bf16x8*)&Ash[cur][aoff];
        const bf16x8 a_lo = *(const bf16x8*)&Asl[cur][aoff];
#pragma unroll
        for (int ct = 0; ct < 4; ++ct) {
          const int brow = ct * 16 + lc;
          const int boff = brow * 64 + ((s * 32 + lg * 8) ^ ((brow & 7) << 3));
          const bf16x8 b_hi = *(const bf16x8*)&Wsh[boff];
          const bf16x8 b_lo = *(const bf16x8*)&Wsl[boff];
          acc[ar][ct] = __builtin_amdgcn_mfma_f32_16x16x32_bf16(a_hi, b_hi, acc[ar][ct], 0, 0, 0);
          acc[ar][ct] = __builtin_amdgcn_mfma_f32_16x16x32_bf16(a_hi, b_lo, acc[ar][ct], 0, 0, 0);
          acc[ar][ct] = __builtin_amdgcn_mfma_f32_16x16x32_bf16(a_lo, b_hi, acc[ar][ct], 0, 0, 0);
        }
      }
    }
    __builtin_amdgcn_s_setprio(0);
  }

  // Epilogue. C/D: lane -> row 4*lg+reg, col lc (within 16-col tile ct).
#pragma unroll
  for (int ar = 0; ar < 2; ++ar) {
#pragma unroll
    for (int ct = 0; ct < 4; ++ct) {
#pragma unroll
      for (int reg = 0; reg < 4; ++reg) {
        const float val = acc[ar][ct][reg];
        const int m = mt * 128 + ar * 64 + w * 16 + lg * 4 + reg;
        const int col = ct * 16 + lc;
        if (EPI == EPI_OUT) {
          Cf[(size_t)m * 512 + nt * 64 + col] = val;
        } else {
          unsigned short hi, lo;
          split_rne(val, hi, lo);
          const int b = m >> 11, l = m & 2047;
          if (EPI == EPI_Q) {
            const size_t o = ((size_t)(b * 8 + nt) * 2048 + l) * 64 + col;
            Ch[o] = hi; Cl[o] = lo;
          } else if (EPI == EPI_K) {
            const int kti = l >> 6, r = l & 63;
            const size_t o = ((size_t)((b * 8 + nt) * 32 + kti)) * 4096 +
                             r * 64 + (col ^ ((r & 7) << 3));
            Ch[o] = hi; Cl[o] = lo;
          } else {
            const int kti = l >> 6, key = l & 63;
            const size_t o = ((size_t)((b * 8 + nt) * 32 + kti)) * 4096 +
                             col * 64 + (key ^ ((col & 7) << 3));
            Ch[o] = hi; Cl[o] = lo;
          }
        }
      }
    }
  }
}

// ---------------------------------------------------------------------------
// Flash attention, split-bf16 MFMA. K/V double-buffered: loads for kt+1
// issued right after the single per-tile barrier -> in flight across the
// whole QK^T+softmax+PV phase. Defer-max (exact: skip rescale when no new
// max anywhere in the wave). exp2-domain softmax. LDS 80KB -> 2 blocks/CU.
// ---------------------------------------------------------------------------
__global__ __launch_bounds__(256) void attn_fwd_mfma(
    const unsigned short* __restrict__ qhh, const unsigned short* __restrict__ qhl,
    const unsigned short* __restrict__ khh, const unsigned short* __restrict__ khl,
    const unsigned short* __restrict__ vth, const unsigned short* __restrict__ vtl,
    const int* __restrict__ mask,
    unsigned short* __restrict__ xh, unsigned short* __restrict__ xl) {
  __shared__ unsigned short Ksh_h[2][4096], Ksh_l[2][4096];
  __shared__ unsigned short Vts_h[2][4096], Vts_l[2][4096];
  __shared__ unsigned short Ps_h[4096], Ps_l[4096];

  const int tid = threadIdx.x;
  const int w = tid >> 6, lane = tid & 63, lg = lane >> 4, lc = lane & 15;
  const int qt = blockIdx.x, h = blockIdx.y, b = blockIdx.z;

  const size_t kvbase = (size_t)((b * 8 + h) * 32) * 4096;

  // Q fragments from global (pre-split row-major), once per block.
  const size_t qbase = ((size_t)(b * 8 + h) * 2048 + qt * 64 + w * 16 + lc) * 64;
  bf16x8 qa_hi[2], qa_lo[2];
#pragma unroll
  for (int s = 0; s < 2; ++s) {
    qa_hi[s] = *(const bf16x8*)(qhh + qbase + s * 32 + lg * 8);
    qa_lo[s] = *(const bf16x8*)(qhl + qbase + s * 32 + lg * 8);
  }

  auto issueKV = [&](int kt, int buf) {
    const size_t tb = kvbase + (size_t)kt * 4096;
    const int so = w * 512 + lane * 8;
    gload_lds16(khh + tb + so, &Ksh_h[buf][w * 512]);
    gload_lds16(khh + tb + so + 2048, &Ksh_h[buf][w * 512 + 2048]);
    gload_lds16(khl + tb + so, &Ksh_l[buf][w * 512]);
    gload_lds16(khl + tb + so + 2048, &Ksh_l[buf][w * 512 + 2048]);
    gload_lds16(vth + tb + so, &Vts_h[buf][w * 512]);
    gload_lds16(vth + tb + so + 2048, &Vts_h[buf][w * 512 + 2048]);
    gload_lds16(vtl + tb + so, &Vts_l[buf][w * 512]);
    gload_lds16(vtl + tb + so + 2048, &Vts_l[buf][w * 512 + 2048]);
  };
  issueKV(0, 0);

  float m_run[4] = {-1e30f, -1e30f, -1e30f, -1e30f};
  float l_run[4] = {0.f, 0.f, 0.f, 0.f};
  f32x4 o_acc[4] = {{0, 0, 0, 0}, {0, 0, 0, 0}, {0, 0, 0, 0}, {0, 0, 0, 0}};

  for (int kt = 0; kt < 32; ++kt) {
    const int cur = kt & 1;
    __syncthreads();  // buf[cur] loads drained; buf[cur^1] free
    if (kt < 31) issueKV(kt + 1, cur ^ 1);  // in flight across compute
    int mv[4];
#pragma unroll
    for (int ct = 0; ct < 4; ++ct)
      mv[ct] = mask[b * SEQ + kt * 64 + ct * 16 + lc];

    // ---- QK^T: S[16 q x 64 k] as 4 col-tiles ----
    f32x4 s_acc[4];
    __builtin_amdgcn_s_setprio(1);
#pragma unroll
    for (int ct = 0; ct < 4; ++ct) {
      f32x4 a2 = {0, 0, 0, 0};
#pragma unroll
      for (int s = 0; s < 2; ++s) {
        const int row = ct * 16 + lc;
        const int off = row * 64 + ((s * 32 + lg * 8) ^ ((row & 7) << 3));
        const bf16x8 kb_hi = *(const bf16x8*)&Ksh_h[cur][off];
        const bf16x8 kb_lo = *(const bf16x8*)&Ksh_l[cur][off];
        a2 = __builtin_amdgcn_mfma_f32_16x16x32_bf16(qa_hi[s], kb_hi, a2, 0, 0, 0);
        a2 = __builtin_amdgcn_mfma_f32_16x16x32_bf16(qa_hi[s], kb_lo, a2, 0, 0, 0);
        a2 = __builtin_amdgcn_mfma_f32_16x16x32_bf16(qa_lo[s], kb_hi, a2, 0, 0, 0);
      }
      s_acc[ct] = a2;
    }
    __builtin_amdgcn_s_setprio(0);

    // ---- mask + scale into log2 domain ----
    float sc[4][4];
#pragma unroll
    for (int ct = 0; ct < 4; ++ct) {
      const bool dead = (mv[ct] == 0);
#pragma unroll
      for (int reg = 0; reg < 4; ++reg)
        sc[ct][reg] = dead ? MASKL2 : s_acc[ct][reg] * SCL2;
    }
    // ---- row max (16-lane group reduce) ----
    float rmax[4];
#pragma unroll
    for (int reg = 0; reg < 4; ++reg) {
      float r = fmaxf(fmaxf(sc[0][reg], sc[1][reg]), fmaxf(sc[2][reg], sc[3][reg]));
      r = fmaxf(r, __shfl_xor(r, 1));
      r = fmaxf(r, __shfl_xor(r, 2));
      r = fmaxf(r, __shfl_xor(r, 4));
      r = fmaxf(r, __shfl_xor(r, 8));
      rmax[reg] = r;
    }
    // ---- defer-max rescale (exact: alpha would be exp2(0)=1 when skipped) --
    const bool nonew = (rmax[0] <= m_run[0]) && (rmax[1] <= m_run[1]) &&
                       (rmax[2] <= m_run[2]) && (rmax[3] <= m_run[3]);
    if (!__all(nonew)) {
#pragma unroll
      for (int reg = 0; reg < 4; ++reg) {
        const float mnew = fmaxf(m_run[reg], rmax[reg]);
        const float alpha = __builtin_exp2f(m_run[reg] - mnew);
        m_run[reg] = mnew;
        l_run[reg] *= alpha;
#pragma unroll
        for (int dt = 0; dt < 4; ++dt) o_acc[dt][reg] *= alpha;
      }
    }
    // ---- p = exp2(sc - m), row sum ----
    float p_val[4][4];
#pragma unroll
    for (int reg = 0; reg < 4; ++reg) {
      float rsum = 0.f;
#pragma unroll
      for (int ct = 0; ct < 4; ++ct) {
        const float p = __builtin_exp2f(sc[ct][reg] - m_run[reg]);
        p_val[ct][reg] = p;
        rsum += p;
      }
      rsum += __shfl_xor(rsum, 1);
      rsum += __shfl_xor(rsum, 2);
      rsum += __shfl_xor(rsum, 4);
      rsum += __shfl_xor(rsum, 8);
      l_run[reg] += rsum;
    }

    // ---- P (trunc split) to wave-private LDS rows ----
#pragma unroll
    for (int ct = 0; ct < 4; ++ct)
#pragma unroll
      for (int reg = 0; reg < 4; ++reg) {
        const int row = w * 16 + lg * 4 + reg;
        const int col = ct * 16 + lc;
        unsigned short hi, lo;
        split_trunc(p_val[ct][reg], hi, lo);
        const int off = row * 64 + (col ^ ((row & 7) << 3));
        Ps_h[off] = hi;
        Ps_l[off] = lo;
      }

    // ---- PV: O[16 q x 64 d] += P @ V ----
    __builtin_amdgcn_s_setprio(1);
#pragma unroll
    for (int s = 0; s < 2; ++s) {
      const int arow = w * 16 + lc;
      const int aoff = arow * 64 + ((s * 32 + lg * 8) ^ ((arow & 7) << 3));
      const bf16x8 pa_hi = *(const bf16x8*)&Ps_h[aoff];
      const bf16x8 pa_lo = *(const bf16x8*)&Ps_l[aoff];
#pragma unroll
      for (int dt = 0; dt < 4; ++dt) {
        const int brow = dt * 16 + lc;
        const int boff = brow * 64 + ((s * 32 + lg * 8) ^ ((brow & 7) << 3));
        const bf16x8 vb_hi = *(const bf16x8*)&Vts_h[cur][boff];
        const bf16x8 vb_lo = *(const bf16x8*)&Vts_l[cur][boff];
        o_acc[dt] = __builtin_amdgcn_mfma_f32_16x16x32_bf16(pa_hi, vb_hi, o_acc[dt], 0, 0, 0);
        o_acc[dt] = __builtin_amdgcn_mfma_f32_16x16x32_bf16(pa_hi, vb_lo, o_acc[dt], 0, 0, 0);
        o_acc[dt] = __builtin_amdgcn_mfma_f32_16x16x32_bf16(pa_lo, vb_hi, o_acc[dt], 0, 0, 0);
      }
    }
    __builtin_amdgcn_s_setprio(0);
  }

  // ---- finalize: /l, split, write x tiles for out-proj GEMM ----
#pragma unroll
  for (int reg = 0; reg < 4; ++reg) {
    const float inv = 1.0f / l_run[reg];
    const int row = w * 16 + lg * 4 + reg;
    const size_t tbase = ((size_t)((b * 32 + qt) * 8 + h)) * 4096;
#pragma unroll
    for (int dt = 0; dt < 4; ++dt) {
      const int c = dt * 16 + lc;
      unsigned short hi, lo;
      split_rne(o_acc[dt][reg] * inv, hi, lo);
      const size_t o = tbase + row * 64 + (c ^ ((row & 7) << 3));
      xh[o] = hi;
      xl[o] = lo;
    }
  }
}

// ---------------------------------------------------------------------------
extern "C" void kernel_launch(void* const* d_in, const int* in_sizes, int n_in,
                              void* d_out, int out_size, void* d_ws,
                              size_t ws_size, hipStream_t stream) {
  const float* q = (const float*)d_in[0];
  const float* k = (const float*)d_in[1];
  const float* v = (const float*)d_in[2];
  const int* mask = (const int*)d_in[3];
  const float* w_q = (const float*)d_in[4];
  const float* w_k = (const float*)d_in[5];
  const float* w_v = (const float*)d_in[6];
  const float* w_o = (const float*)d_in[7];
  float* out = (float*)d_out;

  unsigned short* ws = (unsigned short*)d_ws;
  const size_t SZ = 4194304;
  unsigned short* Xh = ws;
  unsigned short* Xl = ws + SZ;
  unsigned short* qh_h = ws + 2 * SZ; unsigned short* qh_l = ws + 3 * SZ;
  unsigned short* kh_h = ws + 4 * SZ; unsigned short* kh_l = ws + 5 * SZ;
  unsigned short* vt_h = ws + 6 * SZ; unsigned short* vt_l = ws + 7 * SZ;

  dim3 blk(256);
  dim3 gs(4096);      // split passes
  dim3 gg(64, 8);     // GEMMs (BM=128)
  dim3 ga(32, 8, 4);  // attention

  split_tile<<<gs, blk, 0, stream>>>(q, Xh, Xl);
  gemm_split<EPI_Q><<<gg, blk, 0, stream>>>(Xh, Xl, w_q, qh_h, qh_l, nullptr);
  split_tile<<<gs, blk, 0, stream>>>(k, Xh, Xl);
  gemm_split<EPI_K><<<gg, blk, 0, stream>>>(Xh, Xl, w_k, kh_h, kh_l, nullptr);
  split_tile<<<gs, blk, 0, stream>>>(v, Xh, Xl);
  gemm_split<EPI_VT><<<gg, blk, 0, stream>>>(Xh, Xl, w_v, vt_h, vt_l, nullptr);
  attn_fwd_mfma<<<ga, blk, 0, stream>>>(qh_h, qh_l, kh_h, kh_l, vt_h, vt_l,
                                        mask, Xh, Xl);
  gemm_split<EPI_OUT><<<gg, blk, 0, stream>>>(Xh, Xl, w_o, nullptr, nullptr, out);
}